// Round 2
// baseline (1272.893 us; speedup 1.0000x reference)
//
#include <hip/hip_runtime.h>

#define SQLEN 2048
#define QKVW 12288
#define NHEADS 16
#define HEADD 256

typedef unsigned short u16;
typedef __bf16 bf16x8 __attribute__((ext_vector_type(8)));
typedef float f32x4 __attribute__((ext_vector_type(4)));

__device__ __forceinline__ float bf2f(u16 u) {
  union { unsigned int i; float f; } v; v.i = ((unsigned int)u) << 16; return v.f;
}
__device__ __forceinline__ u16 f2bf(float f) {
  union { float f; unsigned int i; } v; v.f = f;
  unsigned int x = v.i;
  return (u16)((x + 0x7fffu + ((x >> 16) & 1u)) >> 16);
}

// ---------------------------------------------------------------------------
// f32 -> bf16 elementwise convert (8 elems/thread, float4 loads).
// ---------------------------------------------------------------------------
__global__ __launch_bounds__(256) void f32_to_bf16(
    const float* __restrict__ src, u16* __restrict__ dst) {
  long i = (long)(blockIdx.x * 256 + threadIdx.x) * 8;
  float4 a = *reinterpret_cast<const float4*>(src + i);
  float4 b = *reinterpret_cast<const float4*>(src + i + 4);
  u16 tmp[8] = {f2bf(a.x), f2bf(a.y), f2bf(a.z), f2bf(a.w),
                f2bf(b.x), f2bf(b.y), f2bf(b.z), f2bf(b.w)};
  *reinterpret_cast<uint4*>(dst + i) = *reinterpret_cast<uint4*>(tmp);
}

// ---------------------------------------------------------------------------
// 64x64-tiled transpose f32 src -> bf16 dst, XOR-swizzled LDS.
// dst[c*dst_ld + r] = (bf16)src[r*src_ld + c].  grid: (C/64, R/64)
// ---------------------------------------------------------------------------
__global__ __launch_bounds__(256) void ktranspose_f32(
    const float* __restrict__ src, u16* __restrict__ dst,
    int src_ld, int dst_ld) {
  __shared__ __align__(16) u16 t[64][64];
  const int c0 = blockIdx.x * 64, r0 = blockIdx.y * 64;
  const int tid = threadIdx.x;
  #pragma unroll
  for (int it = 0; it < 2; ++it) {
    int c = tid + it * 256;
    int r = c >> 3, ch = c & 7;
    const float* sp = src + (long)(r0 + r) * src_ld + c0 + ch * 8;
    float4 v0 = *reinterpret_cast<const float4*>(sp);
    float4 v1 = *reinterpret_cast<const float4*>(sp + 4);
    u16 tmp[8] = {f2bf(v0.x), f2bf(v0.y), f2bf(v0.z), f2bf(v0.w),
                  f2bf(v1.x), f2bf(v1.y), f2bf(v1.z), f2bf(v1.w)};
    int sw = ch ^ (r & 7);
    *reinterpret_cast<uint4*>(&t[r][sw * 8]) = *reinterpret_cast<uint4*>(tmp);
  }
  __syncthreads();
  #pragma unroll
  for (int it = 0; it < 2; ++it) {
    int c = tid + it * 256;
    int rr = c >> 3, ch = c & 7;  // rr = src col (dst row), ch = dst col chunk
    u16 tmp[8];
    #pragma unroll
    for (int j = 0; j < 8; ++j) {
      int k = ch * 8 + j;  // src row
      int sw = (rr >> 3) ^ (k & 7);
      tmp[j] = t[k][sw * 8 + (rr & 7)];
    }
    *reinterpret_cast<uint4*>(dst + (long)(c0 + rr) * dst_ld + r0 + ch * 8) =
        *reinterpret_cast<uint4*>(tmp);
  }
}

// ---------------------------------------------------------------------------
// 64x64-tiled bf16 transpose with batch-z offsets (for V -> V^T per head).
// grid: (C/64, R/64, Z); z decomposes as (z>>4, z&15).
// ---------------------------------------------------------------------------
__global__ __launch_bounds__(256) void ktranspose_bf16(
    const u16* __restrict__ src, u16* __restrict__ dst,
    int src_ld, int dst_ld, long src_off,
    long szs1, long szs2, long dzs1, long dzs2) {
  __shared__ __align__(16) u16 t[64][64];
  const int z = blockIdx.z;
  const u16* s = src + src_off + (long)(z >> 4) * szs1 + (long)(z & 15) * szs2;
  u16* d = dst + (long)(z >> 4) * dzs1 + (long)(z & 15) * dzs2;
  const int c0 = blockIdx.x * 64, r0 = blockIdx.y * 64;
  const int tid = threadIdx.x;
  #pragma unroll
  for (int it = 0; it < 2; ++it) {
    int c = tid + it * 256;
    int r = c >> 3, ch = c & 7;
    uint4 v = *reinterpret_cast<const uint4*>(s + (long)(r0 + r) * src_ld + c0 + ch * 8);
    int sw = ch ^ (r & 7);
    *reinterpret_cast<uint4*>(&t[r][sw * 8]) = v;
  }
  __syncthreads();
  #pragma unroll
  for (int it = 0; it < 2; ++it) {
    int c = tid + it * 256;
    int rr = c >> 3, ch = c & 7;
    u16 tmp[8];
    #pragma unroll
    for (int j = 0; j < 8; ++j) {
      int k = ch * 8 + j;
      int sw = (rr >> 3) ^ (k & 7);
      tmp[j] = t[k][sw * 8 + (rr & 7)];
    }
    *reinterpret_cast<uint4*>(d + (long)(c0 + rr) * dst_ld + r0 + ch * 8) =
        *reinterpret_cast<uint4*>(tmp);
  }
}

// ---------------------------------------------------------------------------
// C = A @ BT^T : A[M][K] bf16 row-major, BT[N][K] bf16 row-major.
// OUT_T = u16 (bf16) or float. 128x128 tile, BK=32, 4 waves, 4x4 MFMAs.
// grid: (N/128, M/128)
// ---------------------------------------------------------------------------
template <typename OUT_T>
__global__ __launch_bounds__(256, 2) void gemm_bt(
    const u16* __restrict__ A, const u16* __restrict__ BT, OUT_T* __restrict__ C,
    int M, int N, int K) {
  __shared__ __align__(16) u16 As[128][40];
  __shared__ __align__(16) u16 Bs[128][40];
  const int tid = threadIdx.x;
  const int wave = tid >> 6, lane = tid & 63;
  const int quad = lane >> 4, l16 = lane & 15;
  const int wm = (wave >> 1) * 64, wn = (wave & 1) * 64;
  const long m0 = (long)blockIdx.y * 128, n0 = (long)blockIdx.x * 128;
  const int ar = tid >> 2, ac8 = (tid & 3) * 8;
  f32x4 acc[4][4] = {};
  for (int k0 = 0; k0 < K; k0 += 32) {
    #pragma unroll
    for (int h = 0; h < 2; ++h) {
      int r = ar + h * 64;
      *reinterpret_cast<uint4*>(&As[r][ac8]) =
          *reinterpret_cast<const uint4*>(A + (m0 + r) * (long)K + k0 + ac8);
      *reinterpret_cast<uint4*>(&Bs[r][ac8]) =
          *reinterpret_cast<const uint4*>(BT + (n0 + r) * (long)K + k0 + ac8);
    }
    __syncthreads();
    bf16x8 af[4], bfr[4];
    #pragma unroll
    for (int i = 0; i < 4; ++i)
      af[i] = *reinterpret_cast<const bf16x8*>(&As[wm + i * 16 + l16][quad * 8]);
    #pragma unroll
    for (int i = 0; i < 4; ++i)
      bfr[i] = *reinterpret_cast<const bf16x8*>(&Bs[wn + i * 16 + l16][quad * 8]);
    #pragma unroll
    for (int i = 0; i < 4; ++i)
      #pragma unroll
      for (int j = 0; j < 4; ++j)
        acc[i][j] = __builtin_amdgcn_mfma_f32_16x16x32_bf16(af[i], bfr[j], acc[i][j], 0, 0, 0);
    __syncthreads();
  }
  #pragma unroll
  for (int i = 0; i < 4; ++i)
    #pragma unroll
    for (int j = 0; j < 4; ++j) {
      long col = n0 + wn + j * 16 + l16;
      #pragma unroll
      for (int r = 0; r < 4; ++r) {
        long row = m0 + wm + i * 16 + quad * 4 + r;
        if constexpr (sizeof(OUT_T) == 4)
          C[row * (long)N + col] = acc[i][j][r];
        else
          C[row * (long)N + col] = f2bf(acc[i][j][r]);
      }
    }
}

// ---------------------------------------------------------------------------
// NeoX RoPE in-place on q,k parts of qkv[4096][12288] (bf16).
// ---------------------------------------------------------------------------
__global__ __launch_bounds__(256) void rope_kernel(
    u16* __restrict__ qkv, const int* __restrict__ positions) {
  int idx = blockIdx.x * 256 + threadIdx.x;
  int i = idx & 127;
  int head = (idx >> 7) & 31;
  int row = idx >> 12;
  int col = (head < NHEADS) ? head * HEADD : 4096 + (head - NHEADS) * HEADD;
  u16* p = qkv + (long)row * QKVW + col;
  float x1 = bf2f(p[i]), x2 = bf2f(p[i + 128]);
  float pos = (float)positions[row];
  float inv_freq = exp2f((float)i * (-13.287712379549449f / 128.0f)); // theta^(-i/128)
  float ang = pos * inv_freq;
  float sv, cv;
  sincosf(ang, &sv, &cv);
  p[i] = f2bf(x1 * cv - x2 * sv);
  p[i + 128] = f2bf(x2 * cv + x1 * sv);
}

// ---------------------------------------------------------------------------
// Flash attention, causal. One block = 64 q rows of one (b,h).
// grid: (S/64, B*NH)
// ---------------------------------------------------------------------------
__global__ __launch_bounds__(256, 1) void attn_kernel(
    const u16* __restrict__ qkv, const u16* __restrict__ VT,
    u16* __restrict__ attnout) {
  const int qt = blockIdx.x;
  const int bh = blockIdx.y;
  const int b = bh >> 4, h = bh & 15;
  const int tid = threadIdx.x;
  const int wave = tid >> 6, lane = tid & 63;
  const int quad = lane >> 4, l16 = lane & 15;

  __shared__ __align__(16) u16 Ks[64][264];   // K tile (also Q staging)
  __shared__ __align__(16) u16 Vs[256][72];   // V^T tile: [hd][s]
  __shared__ __align__(16) u16 Ps[64][72];    // P relayout

  const u16* qp = qkv + (long)b * SQLEN * QKVW + h * HEADD;
  const u16* kp = qp + 4096;
  const u16* vtp = VT + (long)bh * HEADD * SQLEN;

  #pragma unroll
  for (int it = 0; it < 8; ++it) {
    int c = tid + it * 256;
    int r = c >> 5, c8 = (c & 31) * 8;
    *reinterpret_cast<uint4*>(&Ks[r][c8]) =
        *reinterpret_cast<const uint4*>(qp + (long)(qt * 64 + r) * QKVW + c8);
  }
  __syncthreads();
  bf16x8 qf[8];
  #pragma unroll
  for (int s = 0; s < 8; ++s)
    qf[s] = *reinterpret_cast<const bf16x8*>(&Ks[wave * 16 + l16][s * 32 + quad * 8]);
  __syncthreads();

  float m_i[4], l_i[4];
  #pragma unroll
  for (int r = 0; r < 4; ++r) { m_i[r] = -INFINITY; l_i[r] = 0.f; }
  f32x4 o[16] = {};
  const float cs = 0.0625f * 1.4426950408889634f;  // scale * log2(e)

  for (int kt = 0; kt <= qt; ++kt) {
    #pragma unroll
    for (int it = 0; it < 8; ++it) {
      int c = tid + it * 256;
      int r = c >> 5, c8 = (c & 31) * 8;
      *reinterpret_cast<uint4*>(&Ks[r][c8]) =
          *reinterpret_cast<const uint4*>(kp + (long)(kt * 64 + r) * QKVW + c8);
    }
    #pragma unroll
    for (int it = 0; it < 8; ++it) {
      int c = tid + it * 256;
      int r = c >> 3, c8 = (c & 7) * 8;
      *reinterpret_cast<uint4*>(&Vs[r][c8]) =
          *reinterpret_cast<const uint4*>(vtp + (long)r * SQLEN + kt * 64 + c8);
    }
    __syncthreads();

    f32x4 sc[4] = {};
    #pragma unroll
    for (int s = 0; s < 8; ++s) {
      #pragma unroll
      for (int nb = 0; nb < 4; ++nb) {
        bf16x8 kf = *reinterpret_cast<const bf16x8*>(&Ks[nb * 16 + l16][s * 32 + quad * 8]);
        sc[nb] = __builtin_amdgcn_mfma_f32_16x16x32_bf16(qf[s], kf, sc[nb], 0, 0, 0);
      }
    }
    const bool diag = (kt == qt);
    #pragma unroll
    for (int nb = 0; nb < 4; ++nb)
      #pragma unroll
      for (int r = 0; r < 4; ++r) {
        float v = sc[nb][r] * cs;
        if (diag) {
          int colL = nb * 16 + l16, rowL = wave * 16 + quad * 4 + r;
          if (colL > rowL) v = -INFINITY;
        }
        sc[nb][r] = v;
      }
    float alpha[4];
    #pragma unroll
    for (int r = 0; r < 4; ++r) {
      float t = fmaxf(fmaxf(sc[0][r], sc[1][r]), fmaxf(sc[2][r], sc[3][r]));
      #pragma unroll
      for (int d = 1; d < 16; d <<= 1) t = fmaxf(t, __shfl_xor(t, d));
      float mn = fmaxf(m_i[r], t);
      alpha[r] = exp2f(m_i[r] - mn);
      m_i[r] = mn;
    }
    #pragma unroll
    for (int r = 0; r < 4; ++r) {
      float t = 0.f;
      #pragma unroll
      for (int nb = 0; nb < 4; ++nb) {
        float p = exp2f(sc[nb][r] - m_i[r]);
        sc[nb][r] = p;
        t += p;
      }
      #pragma unroll
      for (int d = 1; d < 16; d <<= 1) t += __shfl_xor(t, d);
      l_i[r] = l_i[r] * alpha[r] + t;
    }
    #pragma unroll
    for (int nb = 0; nb < 4; ++nb)
      #pragma unroll
      for (int r = 0; r < 4; ++r)
        Ps[wave * 16 + quad * 4 + r][nb * 16 + l16] = f2bf(sc[nb][r]);
    #pragma unroll
    for (int c16 = 0; c16 < 16; ++c16)
      #pragma unroll
      for (int r = 0; r < 4; ++r)
        o[c16][r] *= alpha[r];
    __syncthreads();
    bf16x8 pf[2];
    #pragma unroll
    for (int s2 = 0; s2 < 2; ++s2)
      pf[s2] = *reinterpret_cast<const bf16x8*>(&Ps[wave * 16 + l16][s2 * 32 + quad * 8]);
    #pragma unroll
    for (int c16 = 0; c16 < 16; ++c16) {
      #pragma unroll
      for (int s2 = 0; s2 < 2; ++s2) {
        bf16x8 vf = *reinterpret_cast<const bf16x8*>(&Vs[c16 * 16 + l16][s2 * 32 + quad * 8]);
        o[c16] = __builtin_amdgcn_mfma_f32_16x16x32_bf16(pf[s2], vf, o[c16], 0, 0, 0);
      }
    }
    __syncthreads();
  }
  #pragma unroll
  for (int r = 0; r < 4; ++r) {
    float inv = 1.0f / l_i[r];
    long q = qt * 64 + wave * 16 + quad * 4 + r;
    long rowoff = ((long)b * SQLEN + q) * 4096 + h * HEADD;
    #pragma unroll
    for (int c16 = 0; c16 < 16; ++c16)
      attnout[rowoff + c16 * 16 + l16] = f2bf(o[c16][r] * inv);
  }
}

// ---------------------------------------------------------------------------
extern "C" void kernel_launch(void* const* d_in, const int* in_sizes, int n_in,
                              void* d_out, int out_size, void* d_ws, size_t ws_size,
                              hipStream_t stream) {
  const float* hidden = (const float*)d_in[0];     // f32 per reference
  const int* positions = (const int*)d_in[1];
  const float* Wqkv = (const float*)d_in[2];       // f32 [3072][12288]
  const float* Wo = (const float*)d_in[3];         // f32 [4096][3072]
  float* out = (float*)d_out;                      // f32 per reference
  char* ws = (char*)d_ws;

  // workspace layout (bytes), total 200 MiB:
  //   [0, 100663296)           qkv   4096x12288 bf16
  //   [100663296, 176160768)   WqkvT 12288x3072 bf16 (dead after GEMM1):
  //     [100663296, 134217728)   attn 4096x4096 bf16
  //     [134217728, 159383552)   WoT  3072x4096 bf16
  //   [176160768, 209715200)   hiddenB 4096x3072 bf16 (dead after GEMM1),
  //                            then VT 32x256x2048 bf16
  u16* qkv     = (u16*)(ws);
  u16* WqkvT   = (u16*)(ws + 100663296L);
  u16* attn    = (u16*)(ws + 100663296L);
  u16* WoT     = (u16*)(ws + 134217728L);
  u16* hiddenB = (u16*)(ws + 176160768L);
  u16* VT      = (u16*)(ws + 176160768L);

  // 0) hidden f32 -> bf16  (4096*3072 = 12582912 elems, 8/thread)
  f32_to_bf16<<<dim3(6144, 1, 1), 256, 0, stream>>>(hidden, hiddenB);
  // 1) WqkvT[n][k] bf16 from Wqkv[3072][12288] f32
  ktranspose_f32<<<dim3(192, 48, 1), 256, 0, stream>>>(Wqkv, WqkvT, 12288, 3072);
  // 2) qkv = hiddenB @ WqkvT^T
  gemm_bt<u16><<<dim3(96, 32, 1), 256, 0, stream>>>(
      hiddenB, WqkvT, qkv, 4096, 12288, 3072);
  // 3) RoPE in-place on q,k
  rope_kernel<<<dim3(65536, 1, 1), 256, 0, stream>>>(qkv, positions);
  // 4) VT[bh][hd][s] from qkv v-part (overwrites hiddenB region — now dead)
  ktranspose_bf16<<<dim3(4, 32, 32), 256, 0, stream>>>(
      qkv, VT, 12288, 2048, 8192,
      25165824L, 256L, 8388608L, 524288L);
  // 5) attention
  attn_kernel<<<dim3(32, 32, 1), 256, 0, stream>>>(qkv, VT, attn);
  // 6) WoT[n][k] bf16 from Wo[4096][3072] f32
  ktranspose_f32<<<dim3(48, 64, 1), 256, 0, stream>>>(Wo, WoT, 3072, 4096);
  // 7) out = attn @ WoT^T  (f32 out)
  gemm_bt<float><<<dim3(24, 32, 1), 256, 0, stream>>>(
      attn, WoT, out, 4096, 3072, 4096);
}

// Round 3
// 1070.240 us; speedup vs baseline: 1.1894x; 1.1894x over previous
//
#include <hip/hip_runtime.h>

#define SQLEN 2048
#define QKVW 12288
#define NHEADS 16
#define HEADD 256

typedef unsigned short u16;
typedef __bf16 bf16x8 __attribute__((ext_vector_type(8)));
typedef float f32x4 __attribute__((ext_vector_type(4)));

__device__ __forceinline__ float bf2f(u16 u) {
  union { unsigned int i; float f; } v; v.i = ((unsigned int)u) << 16; return v.f;
}
__device__ __forceinline__ u16 f2bf(float f) {
  union { float f; unsigned int i; } v; v.f = f;
  unsigned int x = v.i;
  return (u16)((x + 0x7fffu + ((x >> 16) & 1u)) >> 16);
}

// async global->LDS, 16B per lane. LDS dest must be wave-uniform base + lane*16.
__device__ __forceinline__ void gl_lds16(const u16* g, u16* l) {
  __builtin_amdgcn_global_load_lds(
      (const __attribute__((address_space(1))) void*)g,
      (__attribute__((address_space(3))) void*)l, 16, 0, 0);
}

// ---------------------------------------------------------------------------
// f32 -> bf16 elementwise convert (8 elems/thread, float4 loads).
// ---------------------------------------------------------------------------
__global__ __launch_bounds__(256) void f32_to_bf16(
    const float* __restrict__ src, u16* __restrict__ dst) {
  long i = (long)(blockIdx.x * 256 + threadIdx.x) * 8;
  float4 a = *reinterpret_cast<const float4*>(src + i);
  float4 b = *reinterpret_cast<const float4*>(src + i + 4);
  u16 tmp[8] = {f2bf(a.x), f2bf(a.y), f2bf(a.z), f2bf(a.w),
                f2bf(b.x), f2bf(b.y), f2bf(b.z), f2bf(b.w)};
  *reinterpret_cast<uint4*>(dst + i) = *reinterpret_cast<uint4*>(tmp);
}

// ---------------------------------------------------------------------------
// 64x64-tiled transpose f32 src -> bf16 dst, XOR-swizzled LDS.
// dst[c*dst_ld + r] = (bf16)src[r*src_ld + c].  grid: (C/64, R/64)
// ---------------------------------------------------------------------------
__global__ __launch_bounds__(256) void ktranspose_f32(
    const float* __restrict__ src, u16* __restrict__ dst,
    int src_ld, int dst_ld) {
  __shared__ __align__(16) u16 t[64][64];
  const int c0 = blockIdx.x * 64, r0 = blockIdx.y * 64;
  const int tid = threadIdx.x;
  #pragma unroll
  for (int it = 0; it < 2; ++it) {
    int c = tid + it * 256;
    int r = c >> 3, ch = c & 7;
    const float* sp = src + (long)(r0 + r) * src_ld + c0 + ch * 8;
    float4 v0 = *reinterpret_cast<const float4*>(sp);
    float4 v1 = *reinterpret_cast<const float4*>(sp + 4);
    u16 tmp[8] = {f2bf(v0.x), f2bf(v0.y), f2bf(v0.z), f2bf(v0.w),
                  f2bf(v1.x), f2bf(v1.y), f2bf(v1.z), f2bf(v1.w)};
    int sw = ch ^ (r & 7);
    *reinterpret_cast<uint4*>(&t[r][sw * 8]) = *reinterpret_cast<uint4*>(tmp);
  }
  __syncthreads();
  #pragma unroll
  for (int it = 0; it < 2; ++it) {
    int c = tid + it * 256;
    int rr = c >> 3, ch = c & 7;
    u16 tmp[8];
    #pragma unroll
    for (int j = 0; j < 8; ++j) {
      int k = ch * 8 + j;
      int sw = (rr >> 3) ^ (k & 7);
      tmp[j] = t[k][sw * 8 + (rr & 7)];
    }
    *reinterpret_cast<uint4*>(dst + (long)(c0 + rr) * dst_ld + r0 + ch * 8) =
        *reinterpret_cast<uint4*>(tmp);
  }
}

// ---------------------------------------------------------------------------
// 64x64-tiled bf16 transpose with batch-z offsets (for V -> V^T per head).
// grid: (C/64, R/64, Z); z decomposes as (z>>4, z&15).
// ---------------------------------------------------------------------------
__global__ __launch_bounds__(256) void ktranspose_bf16(
    const u16* __restrict__ src, u16* __restrict__ dst,
    int src_ld, int dst_ld, long src_off,
    long szs1, long szs2, long dzs1, long dzs2) {
  __shared__ __align__(16) u16 t[64][64];
  const int z = blockIdx.z;
  const u16* s = src + src_off + (long)(z >> 4) * szs1 + (long)(z & 15) * szs2;
  u16* d = dst + (long)(z >> 4) * dzs1 + (long)(z & 15) * dzs2;
  const int c0 = blockIdx.x * 64, r0 = blockIdx.y * 64;
  const int tid = threadIdx.x;
  #pragma unroll
  for (int it = 0; it < 2; ++it) {
    int c = tid + it * 256;
    int r = c >> 3, ch = c & 7;
    uint4 v = *reinterpret_cast<const uint4*>(s + (long)(r0 + r) * src_ld + c0 + ch * 8);
    int sw = ch ^ (r & 7);
    *reinterpret_cast<uint4*>(&t[r][sw * 8]) = v;
  }
  __syncthreads();
  #pragma unroll
  for (int it = 0; it < 2; ++it) {
    int c = tid + it * 256;
    int rr = c >> 3, ch = c & 7;
    u16 tmp[8];
    #pragma unroll
    for (int j = 0; j < 8; ++j) {
      int k = ch * 8 + j;
      int sw = (rr >> 3) ^ (k & 7);
      tmp[j] = t[k][sw * 8 + (rr & 7)];
    }
    *reinterpret_cast<uint4*>(d + (long)(c0 + rr) * dst_ld + r0 + ch * 8) =
        *reinterpret_cast<uint4*>(tmp);
  }
}

// ---------------------------------------------------------------------------
// C = A @ BT^T : A[M][K] bf16 row-major, BT[N][K] bf16 row-major.
// OUT_T = u16 (bf16) or float. 128x128 tile, BK=32, 4 waves, 4x4 MFMAs.
// m97 structure: global_load_lds width=16, UNPADDED LDS (lane-order layout).
// grid: (N/128, M/128)
// ---------------------------------------------------------------------------
template <typename OUT_T>
__global__ __launch_bounds__(256, 2) void gemm_bt(
    const u16* __restrict__ A, const u16* __restrict__ BT, OUT_T* __restrict__ C,
    int M, int N, int K) {
  __shared__ __align__(16) u16 As[128][32];
  __shared__ __align__(16) u16 Bs[128][32];
  const int tid = threadIdx.x;
  const int wave = tid >> 6, lane = tid & 63;
  const int quad = lane >> 4, l16 = lane & 15;
  const int wm = (wave >> 1) * 64, wn = (wave & 1) * 64;
  const long m0 = (long)blockIdx.y * 128, n0 = (long)blockIdx.x * 128;
  const int ar = tid >> 2, ac8 = (tid & 3) * 8;  // LDS dest = tid*16B (lane order)
  f32x4 acc[4][4] = {};
  for (int k0 = 0; k0 < K; k0 += 32) {
    #pragma unroll
    for (int h = 0; h < 2; ++h) {
      int r = ar + h * 64;
      gl_lds16(A + (m0 + r) * (long)K + k0 + ac8, &As[r][ac8]);
      gl_lds16(BT + (n0 + r) * (long)K + k0 + ac8, &Bs[r][ac8]);
    }
    __syncthreads();
    bf16x8 af[4], bfr[4];
    #pragma unroll
    for (int i = 0; i < 4; ++i)
      af[i] = *reinterpret_cast<const bf16x8*>(&As[wm + i * 16 + l16][quad * 8]);
    #pragma unroll
    for (int i = 0; i < 4; ++i)
      bfr[i] = *reinterpret_cast<const bf16x8*>(&Bs[wn + i * 16 + l16][quad * 8]);
    #pragma unroll
    for (int i = 0; i < 4; ++i)
      #pragma unroll
      for (int j = 0; j < 4; ++j)
        acc[i][j] = __builtin_amdgcn_mfma_f32_16x16x32_bf16(af[i], bfr[j], acc[i][j], 0, 0, 0);
    __syncthreads();
  }
  #pragma unroll
  for (int i = 0; i < 4; ++i)
    #pragma unroll
    for (int j = 0; j < 4; ++j) {
      long col = n0 + wn + j * 16 + l16;
      #pragma unroll
      for (int r = 0; r < 4; ++r) {
        long row = m0 + wm + i * 16 + quad * 4 + r;
        if constexpr (sizeof(OUT_T) == 4)
          C[row * (long)N + col] = acc[i][j][r];
        else
          C[row * (long)N + col] = f2bf(acc[i][j][r]);
      }
    }
}

// ---------------------------------------------------------------------------
// NeoX RoPE in-place on q,k parts of qkv[4096][12288] (bf16).
// ---------------------------------------------------------------------------
__global__ __launch_bounds__(256) void rope_kernel(
    u16* __restrict__ qkv, const int* __restrict__ positions) {
  int idx = blockIdx.x * 256 + threadIdx.x;
  int i = idx & 127;
  int head = (idx >> 7) & 31;
  int row = idx >> 12;
  int col = (head < NHEADS) ? head * HEADD : 4096 + (head - NHEADS) * HEADD;
  u16* p = qkv + (long)row * QKVW + col;
  float x1 = bf2f(p[i]), x2 = bf2f(p[i + 128]);
  float pos = (float)positions[row];
  float inv_freq = exp2f((float)i * (-13.287712379549449f / 128.0f)); // theta^(-i/128)
  float ang = pos * inv_freq;
  float sv, cv;
  sincosf(ang, &sv, &cv);
  p[i] = f2bf(x1 * cv - x2 * sv);
  p[i + 128] = f2bf(x2 * cv + x1 * sv);
}

// ---------------------------------------------------------------------------
// Flash attention, causal, load-balanced persistent blocks.
// Block (p, bh) processes q-tiles qt = 31-p then qt = p: (32-p) + (p+1) = 33
// K-tile iterations for every block -> flat makespan. grid: (16, B*NH)
// ---------------------------------------------------------------------------
__global__ __launch_bounds__(256, 1) void attn_kernel(
    const u16* __restrict__ qkv, const u16* __restrict__ VT,
    u16* __restrict__ attnout) {
  const int p = blockIdx.x;
  const int bh = blockIdx.y;
  const int b = bh >> 4, h = bh & 15;
  const int tid = threadIdx.x;
  const int wave = tid >> 6, lane = tid & 63;
  const int quad = lane >> 4, l16 = lane & 15;

  __shared__ __align__(16) u16 Ks[64][264];   // K tile (also Q staging)
  __shared__ __align__(16) u16 Vs[256][72];   // V^T tile: [hd][s]
  __shared__ __align__(16) u16 Ps[64][72];    // P relayout

  const u16* qp = qkv + (long)b * SQLEN * QKVW + h * HEADD;
  const u16* kp = qp + 4096;
  const u16* vtp = VT + (long)bh * HEADD * SQLEN;
  const float cs = 0.0625f * 1.4426950408889634f;  // scale * log2(e)

  for (int half = 0; half < 2; ++half) {
    const int qt = half ? p : 31 - p;  // heavy tile first

    // stage Q tile, pull A-frags (8 k-steps of 32 over HD=256)
    #pragma unroll
    for (int it = 0; it < 8; ++it) {
      int c = tid + it * 256;
      int r = c >> 5, c8 = (c & 31) * 8;
      *reinterpret_cast<uint4*>(&Ks[r][c8]) =
          *reinterpret_cast<const uint4*>(qp + (long)(qt * 64 + r) * QKVW + c8);
    }
    __syncthreads();
    bf16x8 qf[8];
    #pragma unroll
    for (int s = 0; s < 8; ++s)
      qf[s] = *reinterpret_cast<const bf16x8*>(&Ks[wave * 16 + l16][s * 32 + quad * 8]);
    __syncthreads();

    float m_i[4], l_i[4];
    #pragma unroll
    for (int r = 0; r < 4; ++r) { m_i[r] = -INFINITY; l_i[r] = 0.f; }
    f32x4 o[16] = {};

    for (int kt = 0; kt <= qt; ++kt) {
      #pragma unroll
      for (int it = 0; it < 8; ++it) {
        int c = tid + it * 256;
        int r = c >> 5, c8 = (c & 31) * 8;
        *reinterpret_cast<uint4*>(&Ks[r][c8]) =
            *reinterpret_cast<const uint4*>(kp + (long)(kt * 64 + r) * QKVW + c8);
      }
      #pragma unroll
      for (int it = 0; it < 8; ++it) {
        int c = tid + it * 256;
        int r = c >> 3, c8 = (c & 7) * 8;
        *reinterpret_cast<uint4*>(&Vs[r][c8]) =
            *reinterpret_cast<const uint4*>(vtp + (long)r * SQLEN + kt * 64 + c8);
      }
      __syncthreads();

      f32x4 sc[4] = {};
      #pragma unroll
      for (int s = 0; s < 8; ++s) {
        #pragma unroll
        for (int nb = 0; nb < 4; ++nb) {
          bf16x8 kf = *reinterpret_cast<const bf16x8*>(&Ks[nb * 16 + l16][s * 32 + quad * 8]);
          sc[nb] = __builtin_amdgcn_mfma_f32_16x16x32_bf16(qf[s], kf, sc[nb], 0, 0, 0);
        }
      }
      const bool diag = (kt == qt);
      #pragma unroll
      for (int nb = 0; nb < 4; ++nb)
        #pragma unroll
        for (int r = 0; r < 4; ++r) {
          float v = sc[nb][r] * cs;
          if (diag) {
            int colL = nb * 16 + l16, rowL = wave * 16 + quad * 4 + r;
            if (colL > rowL) v = -INFINITY;
          }
          sc[nb][r] = v;
        }
      float alpha[4];
      #pragma unroll
      for (int r = 0; r < 4; ++r) {
        float t = fmaxf(fmaxf(sc[0][r], sc[1][r]), fmaxf(sc[2][r], sc[3][r]));
        #pragma unroll
        for (int d = 1; d < 16; d <<= 1) t = fmaxf(t, __shfl_xor(t, d));
        float mn = fmaxf(m_i[r], t);
        alpha[r] = exp2f(m_i[r] - mn);
        m_i[r] = mn;
      }
      #pragma unroll
      for (int r = 0; r < 4; ++r) {
        float t = 0.f;
        #pragma unroll
        for (int nb = 0; nb < 4; ++nb) {
          float pr = exp2f(sc[nb][r] - m_i[r]);
          sc[nb][r] = pr;
          t += pr;
        }
        #pragma unroll
        for (int d = 1; d < 16; d <<= 1) t += __shfl_xor(t, d);
        l_i[r] = l_i[r] * alpha[r] + t;
      }
      #pragma unroll
      for (int nb = 0; nb < 4; ++nb)
        #pragma unroll
        for (int r = 0; r < 4; ++r)
          Ps[wave * 16 + quad * 4 + r][nb * 16 + l16] = f2bf(sc[nb][r]);
      #pragma unroll
      for (int c16 = 0; c16 < 16; ++c16)
        #pragma unroll
        for (int r = 0; r < 4; ++r)
          o[c16][r] *= alpha[r];
      __syncthreads();
      bf16x8 pf[2];
      #pragma unroll
      for (int s2 = 0; s2 < 2; ++s2)
        pf[s2] = *reinterpret_cast<const bf16x8*>(&Ps[wave * 16 + l16][s2 * 32 + quad * 8]);
      #pragma unroll
      for (int c16 = 0; c16 < 16; ++c16) {
        #pragma unroll
        for (int s2 = 0; s2 < 2; ++s2) {
          bf16x8 vf = *reinterpret_cast<const bf16x8*>(&Vs[c16 * 16 + l16][s2 * 32 + quad * 8]);
          o[c16] = __builtin_amdgcn_mfma_f32_16x16x32_bf16(pf[s2], vf, o[c16], 0, 0, 0);
        }
      }
      __syncthreads();
    }
    #pragma unroll
    for (int r = 0; r < 4; ++r) {
      float inv = 1.0f / l_i[r];
      long q = qt * 64 + wave * 16 + quad * 4 + r;
      long rowoff = ((long)b * SQLEN + q) * 4096 + h * HEADD;
      #pragma unroll
      for (int c16 = 0; c16 < 16; ++c16)
        attnout[rowoff + c16 * 16 + l16] = f2bf(o[c16][r] * inv);
    }
  }
}

// ---------------------------------------------------------------------------
extern "C" void kernel_launch(void* const* d_in, const int* in_sizes, int n_in,
                              void* d_out, int out_size, void* d_ws, size_t ws_size,
                              hipStream_t stream) {
  const float* hidden = (const float*)d_in[0];
  const int* positions = (const int*)d_in[1];
  const float* Wqkv = (const float*)d_in[2];
  const float* Wo = (const float*)d_in[3];
  float* out = (float*)d_out;
  char* ws = (char*)d_ws;

  // workspace layout (bytes), total 200 MiB:
  //   [0, 100663296)           qkv   4096x12288 bf16
  //   [100663296, 176160768)   WqkvT 12288x3072 bf16 (dead after GEMM1):
  //     [100663296, 134217728)   attn 4096x4096 bf16
  //     [134217728, 159383552)   WoT  3072x4096 bf16
  //   [176160768, 209715200)   hiddenB 4096x3072 bf16 (dead after GEMM1),
  //                            then VT 32x256x2048 bf16
  u16* qkv     = (u16*)(ws);
  u16* WqkvT   = (u16*)(ws + 100663296L);
  u16* attn    = (u16*)(ws + 100663296L);
  u16* WoT     = (u16*)(ws + 134217728L);
  u16* hiddenB = (u16*)(ws + 176160768L);
  u16* VT      = (u16*)(ws + 176160768L);

  f32_to_bf16<<<dim3(6144, 1, 1), 256, 0, stream>>>(hidden, hiddenB);
  ktranspose_f32<<<dim3(192, 48, 1), 256, 0, stream>>>(Wqkv, WqkvT, 12288, 3072);
  gemm_bt<u16><<<dim3(96, 32, 1), 256, 0, stream>>>(
      hiddenB, WqkvT, qkv, 4096, 12288, 3072);
  rope_kernel<<<dim3(65536, 1, 1), 256, 0, stream>>>(qkv, positions);
  ktranspose_bf16<<<dim3(4, 32, 32), 256, 0, stream>>>(
      qkv, VT, 12288, 2048, 8192,
      25165824L, 256L, 8388608L, 524288L);
  attn_kernel<<<dim3(16, 32, 1), 256, 0, stream>>>(qkv, VT, attn);
  ktranspose_f32<<<dim3(48, 64, 1), 256, 0, stream>>>(Wo, WoT, 3072, 4096);
  gemm_bt<float><<<dim3(24, 32, 1), 256, 0, stream>>>(
      attn, WoT, out, 4096, 3072, 4096);
}